// Round 10
// baseline (131.835 us; speedup 1.0000x reference)
//
#include <hip/hip_runtime.h>
#include <math.h>

typedef __attribute__((ext_vector_type(8))) short bf16x8;
typedef __attribute__((ext_vector_type(16))) float f32x16;

#define WIN 512
#define META 4
// Q pre-scale folds 1/sqrt(128) AND log2(e): p = exp2(s' - MFIX2) == exp(s/sqrt(D) - 14)
#define QSCALE (0.08838834764831845f * 1.4426950408889634f)
#define MFIX2 20.197730572445487f   // 14 * log2(e)

union U8 { int4 i4; bf16x8 bf; };

static __device__ __forceinline__ unsigned bf16_rne(float x) {
  unsigned u = __float_as_uint(x);
  return (u + 0x7FFFu + ((u >> 16) & 1u)) >> 16;
}
static __device__ __forceinline__ unsigned pk2_rne(float a, float b) {
  return bf16_rne(a) | (bf16_rne(b) << 16);
}
static __device__ __forceinline__ unsigned pk2_tr(float a, float b) {   // truncate
  return (__float_as_uint(a) >> 16) | (__float_as_uint(b) & 0xFFFF0000u);
}
static __device__ __forceinline__ void gload16(const void* g, void* l) {
  __builtin_amdgcn_global_load_lds(
      (const __attribute__((address_space(1))) unsigned int*)g,
      (__attribute__((address_space(3))) unsigned int*)l, 16, 0, 0);
}

// ---------------------------------------------------------------------------
// Pre-pass (verbatim round 7, proven): K,V f32 -> bf16 fragment-major tiles.
//   Kw tile (hk,tj64): 16 frags s x 64 keys x 16B. frag(s,key)=K[key][8s..8s+7].
//   Vw tile (hk,tj64): 8 chunks c x 128 dims x 16B; chunk c covers keys
//   16*(c>>1)+4*(c&1)+{0..3,8..11} (R5 slot permutation), truncation bf16.
// ---------------------------------------------------------------------------
__global__ __launch_bounds__(256) void swa_prep(
    const float* __restrict__ Kg, const float* __restrict__ Vg,
    unsigned short* __restrict__ Kw, unsigned short* __restrict__ Vw)
{
  __shared__ float Kf[64][132];
  __shared__ float Vf[64][132];
  const int tid = threadIdx.x;
  const int hk = blockIdx.x & 7, tj = blockIdx.x >> 3;   // head, 64-key tile
  const int j0 = tj * 64;
  const int krow = tid >> 5;        // 0..7
  const int f4c = tid & 31;         // float4 col
  #pragma unroll
  for (int r = 0; r < 8; ++r) {
    const int key = r * 8 + krow;
    *(float4*)&Kf[key][f4c * 4] =
        *(const float4*)(Kg + (size_t)(j0 + key) * 1024 + hk * 128 + f4c * 4);
    *(float4*)&Vf[key][f4c * 4] =
        *(const float4*)(Vg + (size_t)(j0 + key) * 1024 + hk * 128 + f4c * 4);
  }
  __syncthreads();
  unsigned short* kout = Kw + ((size_t)(hk * 32 + tj)) * 8192;  // 8192 shorts/tile
  #pragma unroll
  for (int p = 0; p < 4; ++p) {
    const int gid = p * 256 + tid;          // frag id = s*64 + key
    const int s = gid >> 6, key = gid & 63;
    const float* src = &Kf[key][s * 8];
    *(int4*)(kout + gid * 8) = make_int4(
        (int)pk2_tr(src[0], src[1]), (int)pk2_tr(src[2], src[3]),
        (int)pk2_tr(src[4], src[5]), (int)pk2_tr(src[6], src[7]));
  }
  unsigned short* vout = Vw + ((size_t)(hk * 32 + tj)) * 8192;
  #pragma unroll
  for (int p = 0; p < 4; ++p) {
    const int fid = p * 256 + tid;          // frag id = c*128 + dim
    const int c = fid >> 7, dim = fid & 127;
    const int kb = 16 * (c >> 1) + 4 * (c & 1);
    *(int4*)(vout + fid * 8) = make_int4(
        (int)pk2_tr(Vf[kb + 0][dim], Vf[kb + 1][dim]),
        (int)pk2_tr(Vf[kb + 2][dim], Vf[kb + 3][dim]),
        (int)pk2_tr(Vf[kb + 8][dim], Vf[kb + 9][dim]),
        (int)pk2_tr(Vf[kb + 10][dim], Vf[kb + 11][dim]));
  }
}

// ---------------------------------------------------------------------------
// Main kernel (round 10): KVBLK=128, K-only LDS, V direct from global.
//   R7<->R9 isolated the wall: #barrier-periods x fixed period cost. So: fewer,
//   longer periods. K tile = 128 keys (2x32KB LDS dbuf, DMA-staged -> no staging
//   registers, avoiding R6's spill trap). V^T fragments are read straight from
//   the fragment-major Vw workspace (L2-resident per XCD, L1-shared across the
//   8 waves) -- no V DMA, no V LDS reads, PV operands hoistable by the
//   scheduler. Heavy block: 6 barrier periods vs R7's 11.
//   Compute per period = 4x 32-key subtiles, no barriers between; per-wave
//   skip guards (R9-proven) handle causal/window/meta edges.
// ---------------------------------------------------------------------------
__global__ __launch_bounds__(512, 2) void swa_fused(
    const float* __restrict__ Qg, const unsigned short* __restrict__ Kw,
    const unsigned short* __restrict__ Vw, float* __restrict__ Og)
{
  __shared__ __align__(16) unsigned short KsB[2][16384];   // 2 x 32 KiB (128k x 128d)

  const int tid = threadIdx.x;
  const int lane = tid & 63, wid = tid >> 6;     // wid 0..7
  const int cl = lane & 31, hl = lane >> 5;
  const int bid = blockIdx.x;
  const int hk = bid & 7;                        // XCD-aligned KV head
  const int bq = bid >> 3;                       // 0..31
  const int q0 = bq << 6;                        // 64-row q tile
  const int h = hk * 4 + (wid & 3);              // this wave's q-head
  const int qw0 = q0 + ((wid >> 2) << 5);        // this wave's 32-row half

  // ---- Q B-fragments from global (once per wave; RNE, pre-scaled) ----
  int4 qf[8];
  {
    const float* qrow = Qg + (size_t)(qw0 + cl) * 4096 + h * 128 + hl * 8;
    #pragma unroll
    for (int kc = 0; kc < 8; ++kc) {
      float4 x = *(const float4*)(qrow + kc * 16);
      float4 y = *(const float4*)(qrow + kc * 16 + 4);
      qf[kc] = make_int4(pk2_rne(x.x*QSCALE, x.y*QSCALE), pk2_rne(x.z*QSCALE, x.w*QSCALE),
                         pk2_rne(y.x*QSCALE, y.y*QSCALE), pk2_rne(y.z*QSCALE, y.w*QSCALE));
    }
  }

  f32x16 acc[4];
  #pragma unroll
  for (int nt = 0; nt < 4; ++nt)
    #pragma unroll
    for (int i = 0; i < 16; ++i) acc[nt][i] = 0.f;
  float lpA = 0.f, lpB = 0.f;

  const int jstart = (q0 > WIN) ? ((q0 - WIN) & ~127) : 0;
  const int sink = (jstart > 0) ? 1 : 0;
  const int niter = ((q0 + 63 - jstart) >> 7) + 1 + sink;

  // ---- DMA one 128-key K tile (32 KB = two 64-key prep tiles) ----
  auto stageK = [&](const int j, unsigned short* kd) {
    const int tj64 = j >> 6;
    #pragma unroll
    for (int h2 = 0; h2 < 2; ++h2) {
      const char* src = (const char*)Kw + (((size_t)(hk * 32 + tj64 + h2)) << 14) + tid * 16;
      char* dst = (char*)kd + h2 * 16384 + tid * 16;
      gload16(src, dst);
      gload16(src + 8192, dst + 8192);
    }
  };

  // ---- one 32-key subtile: QK^T -> softmax -> PV (V from global Vw) ----
  //   kb   = LDS base incl. half64 + key-offset; frag read kb+(2kc+hl)*512+cl*8
  //   vbsh = ushort offset into Vw of this subtile's chunk quad (c = base+hl / base+2+hl)
  auto subtile = [&](const unsigned short* kb, const int jts, const size_t vbsh,
                     const bool fm, float& lp) {
    f32x16 sv;
    #pragma unroll
    for (int i = 0; i < 16; ++i) sv[i] = 0.f;
    __builtin_amdgcn_s_setprio(1);
    #pragma unroll
    for (int kc = 0; kc < 8; ++kc) {
      U8 b; b.i4 = qf[kc];
      U8 a; a.i4 = *(const int4*)(kb + (2 * kc + hl) * 512 + cl * 8);
      sv = __builtin_amdgcn_mfma_f32_32x32x16_bf16(a.bf, b.bf, sv, 0, 0, 0);
    }
    __builtin_amdgcn_s_setprio(0);

    const bool needMask = fm || (jts + 31 > qw0) || (qw0 + 31 - jts > WIN);
    unsigned pk[8];
    const int q = qw0 + cl;
    #pragma unroll
    for (int ri = 0; ri < 16; ri += 2) {
      const int koff = (ri & 3) + 8 * (ri >> 2) + 4 * hl;
      bool okE = true, okO = true;
      if (needMask) {
        const int kE = jts + koff;
        okE = (q >= kE)     && (((q - kE)     <= WIN) || (kE     < META));
        okO = (q >= kE + 1) && (((q - kE - 1) <= WIN) || (kE + 1 < META));
      }
      unsigned uE = okE ? (__float_as_uint(__builtin_amdgcn_exp2f(sv[ri]   - MFIX2)) & 0xFFFF0000u) : 0u;
      unsigned uO = okO ? (__float_as_uint(__builtin_amdgcn_exp2f(sv[ri+1] - MFIX2)) & 0xFFFF0000u) : 0u;
      lp += __uint_as_float(uE) + __uint_as_float(uO);
      pk[ri >> 1] = __builtin_amdgcn_perm(uO, uE, 0x07060302u);
    }

    __builtin_amdgcn_s_setprio(1);
    const unsigned short* vb = Vw + vbsh;
    {
      U8 a0; a0.i4 = make_int4((int)pk[0], (int)pk[1], (int)pk[2], (int)pk[3]);
      #pragma unroll
      for (int nt = 0; nt < 4; ++nt) {
        U8 b; b.i4 = *(const int4*)(vb + hl * 1024 + (nt * 32 + cl) * 8);
        acc[nt] = __builtin_amdgcn_mfma_f32_32x32x16_bf16(a0.bf, b.bf, acc[nt], 0, 0, 0);
      }
      U8 a1; a1.i4 = make_int4((int)pk[4], (int)pk[5], (int)pk[6], (int)pk[7]);
      #pragma unroll
      for (int nt = 0; nt < 4; ++nt) {
        U8 b; b.i4 = *(const int4*)(vb + (2 + hl) * 1024 + (nt * 32 + cl) * 8);
        acc[nt] = __builtin_amdgcn_mfma_f32_32x32x16_bf16(a1.bf, b.bf, acc[nt], 0, 0, 0);
      }
    }
    __builtin_amdgcn_s_setprio(0);
  };

  // ---- prologue: DMA tile(iter 0) into buffer 0 ----
  stageK(sink ? 0 : jstart, KsB[0]);
  __syncthreads();

  for (int t = 0; t < niter; ++t) {
    const bool isSink = (sink != 0) && (t == 0);
    const int jt = isSink ? 0 : jstart + ((t - sink) << 7);
    const int cb = t & 1;

    // DMA tile t+1 into the other buffer (all waves passed barrier(t-1), so
    // no laggard still reads KsB[cb^1]; barrier(t) drains before its use).
    if (t + 1 < niter)
      stageK(jstart + ((t + 1 - sink) << 7), KsB[cb ^ 1]);

    if (isSink) {
      // meta keys live in subtile 0 of the j=0 tile; rest of window handled later
      subtile(&KsB[cb][0], 0, ((size_t)(hk * 32)) * 8192, true, lpA);
    } else {
      const int tj64 = jt >> 6;
      #pragma unroll
      for (int st = 0; st < 4; ++st) {
        const int jts = jt + (st << 5);
        const bool above = (jts > qw0 + 31);                          // causal skip
        const bool below = (jts + 31 < qw0 - WIN) && (jts >= META);   // window skip
        if (!above && !below) {
          subtile(&KsB[cb][(st >> 1) * 8192 + (st & 1) * 256], jts,
                  ((size_t)(hk * 32 + tj64 + (st >> 1))) * 8192 + (size_t)(st & 1) * 4096,
                  false, (st & 1) ? lpB : lpA);
        }
      }
    }

    __syncthreads();   // all waves done with KsB[cb]; DMA(t+1) drained
  }

  // ---- epilogue: l = own + partner-half partial; broadcast per q-row; store --
  const float lp = lpA + lpB;
  const float ltot = lp + __shfl_xor(lp, 32);
  const float inv = __fdividef(1.0f, ltot);
  #pragma unroll
  for (int ri = 0; ri < 16; ++ri) {
    const int rl = (ri & 3) + 8 * (ri >> 2) + 4 * hl;
    const float invq = __shfl(inv, rl, 64);
    #pragma unroll
    for (int nt = 0; nt < 4; ++nt) {
      Og[(size_t)(qw0 + rl) * 4096 + h * 128 + nt * 32 + cl] = acc[nt][ri] * invq;
    }
  }
}

extern "C" void kernel_launch(void* const* d_in, const int* in_sizes, int n_in,
                              void* d_out, int out_size, void* d_ws, size_t ws_size,
                              hipStream_t stream) {
  const float* Q = (const float*)d_in[0];
  const float* K = (const float*)d_in[1];
  const float* V = (const float*)d_in[2];
  float* O = (float*)d_out;
  unsigned short* Kw = (unsigned short*)d_ws;             // 4 MiB
  unsigned short* Vw = Kw + (size_t)8 * 32 * 8192;        // 4 MiB (needs ws >= 8 MiB)
  hipLaunchKernelGGL(swa_prep, dim3(256), dim3(256), 0, stream, K, V, Kw, Vw);
  hipLaunchKernelGGL(swa_fused, dim3(256), dim3(512), 0, stream, Q, Kw, Vw, O);
}

// Round 11
// 121.377 us; speedup vs baseline: 1.0862x; 1.0862x over previous
//
#include <hip/hip_runtime.h>
#include <math.h>

typedef __attribute__((ext_vector_type(8))) short bf16x8;
typedef __attribute__((ext_vector_type(16))) float f32x16;

#define WIN 512
#define META 4
// Q pre-scale folds 1/sqrt(128) AND log2(e): p = exp2(s' - MFIX2) == exp(s/sqrt(D) - 14)
#define QSCALE (0.08838834764831845f * 1.4426950408889634f)
#define MFIX2 20.197730572445487f   // 14 * log2(e)

union U8 { int4 i4; bf16x8 bf; };

static __device__ __forceinline__ unsigned bf16_rne(float x) {
  unsigned u = __float_as_uint(x);
  return (u + 0x7FFFu + ((u >> 16) & 1u)) >> 16;
}
static __device__ __forceinline__ unsigned pk2_rne(float a, float b) {
  return bf16_rne(a) | (bf16_rne(b) << 16);
}
static __device__ __forceinline__ unsigned pk2_tr(float a, float b) {   // truncate
  return (__float_as_uint(a) >> 16) | (__float_as_uint(b) & 0xFFFF0000u);
}
static __device__ __forceinline__ void gload16(const void* g, void* l) {
  __builtin_amdgcn_global_load_lds(
      (const __attribute__((address_space(1))) unsigned int*)g,
      (__attribute__((address_space(3))) unsigned int*)l, 16, 0, 0);
}

// ---------------------------------------------------------------------------
// Pre-pass (verbatim round 7, proven): K,V f32 -> bf16 fragment-major tiles.
// ---------------------------------------------------------------------------
__global__ __launch_bounds__(256) void swa_prep(
    const float* __restrict__ Kg, const float* __restrict__ Vg,
    unsigned short* __restrict__ Kw, unsigned short* __restrict__ Vw)
{
  __shared__ float Kf[64][132];
  __shared__ float Vf[64][132];
  const int tid = threadIdx.x;
  const int hk = blockIdx.x & 7, tj = blockIdx.x >> 3;   // head, 64-key tile
  const int j0 = tj * 64;
  const int krow = tid >> 5;        // 0..7
  const int f4c = tid & 31;         // float4 col
  #pragma unroll
  for (int r = 0; r < 8; ++r) {
    const int key = r * 8 + krow;
    *(float4*)&Kf[key][f4c * 4] =
        *(const float4*)(Kg + (size_t)(j0 + key) * 1024 + hk * 128 + f4c * 4);
    *(float4*)&Vf[key][f4c * 4] =
        *(const float4*)(Vg + (size_t)(j0 + key) * 1024 + hk * 128 + f4c * 4);
  }
  __syncthreads();
  unsigned short* kout = Kw + ((size_t)(hk * 32 + tj)) * 8192;  // 8192 shorts/tile
  #pragma unroll
  for (int p = 0; p < 4; ++p) {
    const int gid = p * 256 + tid;          // frag id = s*64 + key
    const int s = gid >> 6, key = gid & 63;
    const float* src = &Kf[key][s * 8];
    *(int4*)(kout + gid * 8) = make_int4(
        (int)pk2_tr(src[0], src[1]), (int)pk2_tr(src[2], src[3]),
        (int)pk2_tr(src[4], src[5]), (int)pk2_tr(src[6], src[7]));
  }
  unsigned short* vout = Vw + ((size_t)(hk * 32 + tj)) * 8192;
  #pragma unroll
  for (int p = 0; p < 4; ++p) {
    const int fid = p * 256 + tid;          // frag id = c*128 + dim
    const int c = fid >> 7, dim = fid & 127;
    const int kb = 16 * (c >> 1) + 4 * (c & 1);
    *(int4*)(vout + fid * 8) = make_int4(
        (int)pk2_tr(Vf[kb + 0][dim], Vf[kb + 1][dim]),
        (int)pk2_tr(Vf[kb + 2][dim], Vf[kb + 3][dim]),
        (int)pk2_tr(Vf[kb + 8][dim], Vf[kb + 9][dim]),
        (int)pk2_tr(Vf[kb + 10][dim], Vf[kb + 11][dim]));
  }
}

// ---------------------------------------------------------------------------
// Main kernel (round 11) = R7 (43us reference) with the vmcnt(0) barrier drain
// removed (T4 counted-vmcnt):
//   - K ring of 3, V ring of 4 (defPV reads V[t-1]; stage(t+2) writes V[(t+2)%4]
//     with t+2-(t-1)=3 != 0 mod 4 -> never aliases). LDS 112 KB, 1 block/CU.
//   - per iter: s_waitcnt vmcnt(4)  (only tile t's 4 loads must be done; the
//     t+1 batch stays IN FLIGHT across the barrier) -> s_barrier ->
//     issue stage(t+2) -> defPV/QK/softmax/PV verbatim R7.
//   - DMA gets ~2 periods to land instead of <1; no full-drain convoy.
//   Safety: leader at barrier(t+1) writes K[(t-1)%3] / V[(t+2)%4]; every reader
//   of those buffers finished before barrier(t) (1-barrier/iter keeps waves
//   within one period). Laggard in compute(t) reads K[t%3], V[t%4], V[(t-1)%4]
//   -- all disjoint from any concurrent DMA target. sched_barrier(0) fences
//   hoisting across the raw barrier.
// ---------------------------------------------------------------------------
__global__ __launch_bounds__(512, 2) void swa_fused(
    const float* __restrict__ Qg, const unsigned short* __restrict__ Kw,
    const unsigned short* __restrict__ Vw, float* __restrict__ Og)
{
  __shared__ __align__(16) unsigned short KsB[3][8192];   // 3 x 16 KiB
  __shared__ __align__(16) unsigned short VtB[4][8192];   // 4 x 16 KiB

  const int tid = threadIdx.x;
  const int lane = tid & 63, wid = tid >> 6;
  const int cl = lane & 31, hl = lane >> 5;
  const int bid = blockIdx.x;
  const int hk = bid & 7;                    // XCD-aligned KV head
  const int bq = bid >> 3;                   // 0..31
  const int q0 = bq << 6;                    // 64-row q tile
  const int h = hk * 4 + (wid & 3);          // this wave's q-head
  const int qw0 = q0 + ((wid >> 2) << 5);    // this wave's 32-row half

  // ---- Q B-fragments from global (once per wave; RNE, pre-scaled) ----
  int4 qf[8];
  {
    const float* qrow = Qg + (size_t)(qw0 + cl) * 4096 + h * 128 + hl * 8;
    #pragma unroll
    for (int kc = 0; kc < 8; ++kc) {
      float4 x = *(const float4*)(qrow + kc * 16);
      float4 y = *(const float4*)(qrow + kc * 16 + 4);
      qf[kc] = make_int4(pk2_rne(x.x*QSCALE, x.y*QSCALE), pk2_rne(x.z*QSCALE, x.w*QSCALE),
                         pk2_rne(y.x*QSCALE, y.y*QSCALE), pk2_rne(y.z*QSCALE, y.w*QSCALE));
    }
  }

  f32x16 acc[4];
  #pragma unroll
  for (int nt = 0; nt < 4; ++nt)
    #pragma unroll
    for (int i = 0; i < 16; ++i) acc[nt][i] = 0.f;
  float lpA = 0.f, lpB = 0.f;

  const int jstart = (q0 > WIN) ? ((q0 - WIN) & ~63) : 0;
  const int sink = (jstart > 0) ? 1 : 0;
  const int niter = ((q0 + 63 - jstart) >> 6) + 1 + sink;
  const int tj0 = jstart >> 6;

  // ---- DMA the K+V tile for iteration index t (exactly 4 gloads/thread) ----
  auto stageT = [&](const int t) {
    const int tj = (sink && t == 0) ? 0 : tj0 + t - sink;
    const size_t base = ((size_t)(hk * 32 + tj)) << 14;   // 16384 B per tile
    unsigned short* kd = KsB[t % 3];
    unsigned short* vd = VtB[t % 4];
    const char* ks = (const char*)Kw + base + tid * 16;
    gload16(ks, (char*)kd + tid * 16);
    gload16(ks + 8192, (char*)kd + tid * 16 + 8192);
    const char* vs = (const char*)Vw + base + tid * 16;
    gload16(vs, (char*)vd + tid * 16);
    gload16(vs + 8192, (char*)vd + tid * 16 + 8192);
  };

  // P-pack: dst = (a>>16)|(b&0xFFFF0000) == perm(b, a, 0x07060302)
  #define MKA(P, o) make_int4( \
      (int)__builtin_amdgcn_perm(P[(o)+1], P[(o)+0], 0x07060302u), \
      (int)__builtin_amdgcn_perm(P[(o)+3], P[(o)+2], 0x07060302u), \
      (int)__builtin_amdgcn_perm(P[(o)+5], P[(o)+4], 0x07060302u), \
      (int)__builtin_amdgcn_perm(P[(o)+7], P[(o)+6], 0x07060302u))

  // PV: one A-group vs 4 output quadrants; Vb = chunk-major V^T buffer
  auto pv4 = [&](const unsigned short* Vb, const int kc, const int4 aw) {
    U8 a; a.i4 = aw;
    #pragma unroll
    for (int nt = 0; nt < 4; ++nt) {
      U8 b; b.i4 = *(const int4*)(Vb + kc * 2048 + hl * 1024 + nt * 256 + cl * 8);
      acc[nt] = __builtin_amdgcn_mfma_f32_32x32x16_bf16(a.bf, b.bf, acc[nt], 0, 0, 0);
    }
  };

  unsigned pu1[16];   // persistent: keys 32..63 P of previous tile (deferred PV)
  #pragma unroll
  for (int i = 0; i < 16; ++i) pu1[i] = 0u;

  // ---- prologue: issue DMA for tiles 0 and 1 (stay in flight) ----
  stageT(0);
  if (niter > 1) stageT(1);

  for (int t = 0; t < niter; ++t) {
    const bool isSink = (sink != 0) && (t == 0);
    const int jt = isSink ? 0 : jstart + ((t - sink) << 6);
    const bool needMask = (jt + 63 > qw0) || (qw0 + 31 - jt > WIN);
    const unsigned short* kCur = KsB[t % 3];
    const unsigned short* vCur = VtB[t % 4];

    // ---- counted wait: only tile t's 4 loads must be complete ----
    if (t < niter - 1) {
      asm volatile("s_waitcnt vmcnt(4)" ::: "memory");
    } else {
      asm volatile("s_waitcnt vmcnt(0)" ::: "memory");
    }
    __builtin_amdgcn_s_barrier();
    __builtin_amdgcn_sched_barrier(0);

    // ---- issue DMA for tile t+2 (post-barrier: all compute(t-1) reads done) --
    if (t + 2 < niter) stageT(t + 2);

    // ---- deferred PV: kc=2,3 of tile t-1 (pu1), V^T from V[(t-1)%4] ----
    if (t > sink) {
      const unsigned short* vPrv = VtB[(t - 1) % 4];
      __builtin_amdgcn_s_setprio(1);
      pv4(vPrv, 2, MKA(pu1, 0));
      pv4(vPrv, 3, MKA(pu1, 8));
      __builtin_amdgcn_s_setprio(0);
    }

    // ---- S^T = K·Q^T (A = K frags, lane-contiguous reads) ----
    f32x16 s0v, s1v;
    #pragma unroll
    for (int i = 0; i < 16; ++i) { s0v[i] = 0.f; s1v[i] = 0.f; }
    __builtin_amdgcn_s_setprio(1);
    if (isSink) {
      #pragma unroll
      for (int kc = 0; kc < 8; ++kc) {
        U8 b; b.i4 = qf[kc];
        U8 a0; a0.i4 = *(const int4*)(kCur + kc * 1024 + hl * 512 + cl * 8);
        s0v = __builtin_amdgcn_mfma_f32_32x32x16_bf16(a0.bf, b.bf, s0v, 0, 0, 0);
      }
    } else {
      #pragma unroll
      for (int kc = 0; kc < 8; ++kc) {
        U8 b; b.i4 = qf[kc];
        U8 a0; a0.i4 = *(const int4*)(kCur + kc * 1024 + hl * 512 + cl * 8);
        s0v = __builtin_amdgcn_mfma_f32_32x32x16_bf16(a0.bf, b.bf, s0v, 0, 0, 0);
        U8 a1; a1.i4 = *(const int4*)(kCur + kc * 1024 + hl * 512 + 256 + cl * 8);
        s1v = __builtin_amdgcn_mfma_f32_32x32x16_bf16(a1.bf, b.bf, s1v, 0, 0, 0);
      }
    }
    __builtin_amdgcn_s_setprio(0);

    // ---- softmax (fixed max): p = exp2(s' - 14*log2e), bf16-truncated ----
    unsigned pu0[16];
    const int q = qw0 + cl;
    #pragma unroll
    for (int ri = 0; ri < 16; ++ri) {
      const int koff = (ri & 3) + 8 * (ri >> 2) + 4 * hl;
      bool ok0 = true, ok1 = true;
      if (needMask) {
        const int k0v = jt + koff, k1v = jt + 32 + koff;
        ok0 = (q >= k0v) && (((q - k0v) <= WIN) || (k0v < META));
        ok1 = (q >= k1v) && (((q - k1v) <= WIN) || (k1v < META));
      }
      unsigned u0 = ok0 ? (__float_as_uint(__builtin_amdgcn_exp2f(s0v[ri] - MFIX2)) & 0xFFFF0000u) : 0u;
      pu0[ri] = u0;
      lpA += __uint_as_float(u0);
      if (!isSink) {
        unsigned u1 = ok1 ? (__float_as_uint(__builtin_amdgcn_exp2f(s1v[ri] - MFIX2)) & 0xFFFF0000u) : 0u;
        pu1[ri] = u1;
        lpB += __uint_as_float(u1);
      }
    }

    // ---- immediate PV: kc=0,1 from pu0 (keys 0..31 of this tile) ----
    __builtin_amdgcn_s_setprio(1);
    pv4(vCur, 0, MKA(pu0, 0));
    if (!isSink) pv4(vCur, 1, MKA(pu0, 8));
    __builtin_amdgcn_s_setprio(0);
  }

  // ---- flush: deferred PV kc=2,3 of the last tile ----
  {
    const unsigned short* vPrv = VtB[(niter - 1) % 4];
    pv4(vPrv, 2, MKA(pu1, 0));
    pv4(vPrv, 3, MKA(pu1, 8));
  }
  #undef MKA

  // ---- epilogue: l = own + partner-half partial; broadcast per q-row; store --
  const float lp = lpA + lpB;
  const float ltot = lp + __shfl_xor(lp, 32);
  const float inv = __fdividef(1.0f, ltot);
  #pragma unroll
  for (int ri = 0; ri < 16; ++ri) {
    const int rl = (ri & 3) + 8 * (ri >> 2) + 4 * hl;
    const float invq = __shfl(inv, rl, 64);
    #pragma unroll
    for (int nt = 0; nt < 4; ++nt) {
      Og[(size_t)(qw0 + rl) * 4096 + h * 128 + nt * 32 + cl] = acc[nt][ri] * invq;
    }
  }
}

extern "C" void kernel_launch(void* const* d_in, const int* in_sizes, int n_in,
                              void* d_out, int out_size, void* d_ws, size_t ws_size,
                              hipStream_t stream) {
  const float* Q = (const float*)d_in[0];
  const float* K = (const float*)d_in[1];
  const float* V = (const float*)d_in[2];
  float* O = (float*)d_out;
  unsigned short* Kw = (unsigned short*)d_ws;             // 4 MiB
  unsigned short* Vw = Kw + (size_t)8 * 32 * 8192;        // 4 MiB (needs ws >= 8 MiB)
  hipLaunchKernelGGL(swa_prep, dim3(256), dim3(256), 0, stream, K, V, Kw, Vw);
  hipLaunchKernelGGL(swa_fused, dim3(256), dim3(512), 0, stream, Q, Kw, Vw, O);
}